// Round 4
// baseline (127.386 us; speedup 1.0000x reference)
//
#include <hip/hip_runtime.h>
#include <hip/hip_bf16.h>

#define PROJ 128
#define KPAD 192
#define EPS 1e-5f

typedef __attribute__((ext_vector_type(4))) float f32x4;
typedef __attribute__((ext_vector_type(8))) short bf16x8;
typedef __attribute__((ext_vector_type(4))) unsigned int u32x4;

__device__ inline float bflo(unsigned u){ union{unsigned x;float f;}c; c.x = u<<16; return c.f; }
__device__ inline float bfhi(unsigned u){ union{unsigned x;float f;}c; c.x = u & 0xffff0000u; return c.f; }
__device__ inline float bf2f(unsigned short u){ union{unsigned x;float f;}c; c.x = ((unsigned)u)<<16; return c.f; }
__device__ inline unsigned short f2bf(float f){
    union{float f; unsigned u;} c; c.f = f;
    unsigned r = c.u + 0x7fff + ((c.u >> 16) & 1);
    return (unsigned short)(r >> 16);
}

// ================= prep: all weight conversion + src build + cinp pads ===========
__global__ __launch_bounds__(256) void prep_all(
    const float* __restrict__ W_proj, const float* __restrict__ Wq,
    const float* __restrict__ Wk, const float* __restrict__ Wv,
    const float* __restrict__ Wo, const float* __restrict__ Ws,
    const float* __restrict__ convw, const float* __restrict__ input,
    unsigned short* __restrict__ Wpb, unsigned short* __restrict__ Wqb,
    unsigned short* __restrict__ Wkb, unsigned short* __restrict__ Wvb,
    unsigned short* __restrict__ Wob, unsigned short* __restrict__ Wsb,
    unsigned short* __restrict__ Wcb, unsigned short* __restrict__ srcb,
    unsigned short* __restrict__ cinp, int L, int T)
{
    int idx = blockIdx.x * 256 + threadIdx.x;
    if (idx < 245760) {
        int r = idx / 192, c = idx % 192;
        Wpb[idx] = (c < 136) ? f2bf(W_proj[(size_t)r * 136 + c]) : (unsigned short)0;
        return;
    }
    idx -= 245760;
    if (idx < 65536) { Wqb[idx] = f2bf(Wq[idx]); return; }
    idx -= 65536;
    if (idx < 49152) {
        int r = idx / 192, c = idx % 192;
        Wkb[idx] = (c < 136) ? f2bf(Wk[(size_t)r * 136 + c]) : (unsigned short)0;
        return;
    }
    idx -= 49152;
    if (idx < 49152) {
        int r = idx / 192, c = idx % 192;
        Wvb[idx] = (c < 136) ? f2bf(Wv[(size_t)r * 136 + c]) : (unsigned short)0;
        return;
    }
    idx -= 49152;
    if (idx < 65536) { Wob[idx] = f2bf(Wo[idx]); return; }
    idx -= 65536;
    if (idx < 65536) { Wsb[idx] = f2bf(Ws[idx]); return; }
    idx -= 65536;
    if (idx < 786432) {
        int l = idx / 196608;
        int r = idx % 196608;
        int o = r / 768, kc = r % 768;
        int kt = kc / 256, ci = kc % 256;
        Wcb[idx] = f2bf(convw[(((size_t)l * 256 + o) * 256 + ci) * 3 + kt]);
        return;
    }
    idx -= 786432;
    if (idx < L * KPAD) {
        int n = idx / KPAD, c = idx % KPAD;
        float v = 0.f;
        if (c < PROJ) v = input[(size_t)n * PROJ + c];
        else if (c < PROJ + 8) {
            int i = c - PROJ;
            int mask = (2 << i) - 1;
            v = (float)(n & mask) / (float)(1 << i);
        }
        srcb[idx] = f2bf(v);
        return;
    }
    idx -= L * KPAD;
    if (idx < 512) {
        int row = idx >> 8, c = idx & 255;
        size_t o = (row == 0) ? (size_t)c : (size_t)(T + 1) * 256 + c;
        cinp[o] = 0;
    }
}

// ================= shared 64x128 GEMM core =================
__device__ __forceinline__ void gemm_core_64x128(
    unsigned short (&As)[64][72], unsigned short (&Bs)[128][72],
    const unsigned short* __restrict__ A, int lda,
    const unsigned short* __restrict__ B, int ldb,
    const float* __restrict__ bias,
    unsigned short* __restrict__ C, int ldc,
    int K, int m0, int n0)
{
    const int tid = threadIdx.x;
    const int lane = tid & 63;
    const int wid = tid >> 6;
    const int wm = wid >> 1, wn = wid & 1;

    const int ar = tid >> 2, asg = tid & 3;
    const int br = tid >> 1, bsg = tid & 1;

    const unsigned short* Ap = A + (size_t)(m0 + ar) * lda + asg * 16;
    const unsigned short* Bp = B + (size_t)(n0 + br) * ldb + bsg * 32;

    u32x4 ra0, ra1, rb0, rb1, rb2, rb3;
    auto loadregs = [&](int k0) {
        ra0 = *(const u32x4*)(Ap + k0);
        ra1 = *(const u32x4*)(Ap + k0 + 8);
        rb0 = *(const u32x4*)(Bp + k0);
        rb1 = *(const u32x4*)(Bp + k0 + 8);
        rb2 = *(const u32x4*)(Bp + k0 + 16);
        rb3 = *(const u32x4*)(Bp + k0 + 24);
    };
    auto stlds = [&]() {
        *(u32x4*)&As[ar][asg * 16]      = ra0;
        *(u32x4*)&As[ar][asg * 16 + 8]  = ra1;
        *(u32x4*)&Bs[br][bsg * 32]      = rb0;
        *(u32x4*)&Bs[br][bsg * 32 + 8]  = rb1;
        *(u32x4*)&Bs[br][bsg * 32 + 16] = rb2;
        *(u32x4*)&Bs[br][bsg * 32 + 24] = rb3;
    };

    f32x4 acc[2][4];
    #pragma unroll
    for (int i = 0; i < 2; ++i)
        #pragma unroll
        for (int j = 0; j < 4; ++j) acc[i][j] = (f32x4){0.f, 0.f, 0.f, 0.f};

    loadregs(0);
    stlds();
    __syncthreads();

    const int rowf = lane & 15, kb = lane >> 4;
    const int ktiles = K >> 6;
    for (int kt = 0; kt < ktiles; ++kt) {
        if (kt + 1 < ktiles) loadregs((kt + 1) << 6);
        #pragma unroll
        for (int ks = 0; ks < 2; ++ks) {
            bf16x8 af[2], bfr[4];
            #pragma unroll
            for (int i = 0; i < 2; ++i)
                af[i] = *(const bf16x8*)&As[wm * 32 + i * 16 + rowf][ks * 32 + kb * 8];
            #pragma unroll
            for (int j = 0; j < 4; ++j)
                bfr[j] = *(const bf16x8*)&Bs[wn * 64 + j * 16 + rowf][ks * 32 + kb * 8];
            #pragma unroll
            for (int i = 0; i < 2; ++i)
                #pragma unroll
                for (int j = 0; j < 4; ++j)
                    acc[i][j] = __builtin_amdgcn_mfma_f32_16x16x32_bf16(af[i], bfr[j], acc[i][j], 0, 0, 0);
        }
        __syncthreads();
        if (kt + 1 < ktiles) { stlds(); __syncthreads(); }
    }

    const int rq = lane >> 4;
    #pragma unroll
    for (int i = 0; i < 2; ++i) {
        int gm = m0 + wm * 32 + i * 16 + rq * 4;
        #pragma unroll
        for (int j = 0; j < 4; ++j) {
            int gn = n0 + wn * 64 + j * 16 + rowf;
            float bv = bias[gn];
            #pragma unroll
            for (int r = 0; r < 4; ++r)
                C[(size_t)(gm + r) * ldc + gn] = f2bf(acc[i][j][r] + bv);
        }
    }
}

__global__ __launch_bounds__(256) void gemm_proj(
    const unsigned short* __restrict__ A, int lda,
    const unsigned short* __restrict__ B, int ldb,
    const float* __restrict__ bias,
    unsigned short* __restrict__ C, int ldc, int K)
{
    __shared__ unsigned short As[64][72];
    __shared__ unsigned short Bs[128][72];
    gemm_core_64x128(As, Bs, A, lda, B, ldb, bias, C, ldc, K,
                     blockIdx.y * 64, blockIdx.x * 128);
}

// q/k/v in one launch: blocks [0,320)=q, [320,384)=k, [384,448)=v
__global__ __launch_bounds__(256) void qkv_fused(
    const unsigned short* __restrict__ tgt,
    const unsigned short* __restrict__ src,
    const unsigned short* __restrict__ Wqb,
    const unsigned short* __restrict__ Wkb,
    const unsigned short* __restrict__ Wvb,
    const float* __restrict__ bq, const float* __restrict__ bk,
    const float* __restrict__ bv,
    unsigned short* __restrict__ qb, unsigned short* __restrict__ kb,
    unsigned short* __restrict__ vb)
{
    __shared__ unsigned short As[64][72];
    __shared__ unsigned short Bs[128][72];
    int bi = blockIdx.x;
    const unsigned short *A, *B;
    const float* bias;
    unsigned short* C;
    int lda, ldb, K, m0, n0;
    if (bi < 320) {
        A = tgt; B = Wqb; bias = bq; C = qb; lda = 256; ldb = 256; K = 256;
        m0 = (bi >> 1) * 64; n0 = (bi & 1) * 128;
    } else if (bi < 384) {
        int t = bi - 320;
        A = src; B = Wkb; bias = bk; C = kb; lda = KPAD; ldb = 192; K = 192;
        m0 = (t >> 1) * 64; n0 = (t & 1) * 128;
    } else {
        int t = bi - 384;
        A = src; B = Wvb; bias = bv; C = vb; lda = KPAD; ldb = 192; K = 192;
        m0 = (t >> 1) * 64; n0 = (t & 1) * 128;
    }
    gemm_core_64x128(As, Bs, A, lda, B, ldb, bias, C, 256, K, m0, n0);
}

// ================= 64x256-tile GEMM with fused LayerNorm epilogue (Wo path) ======
// cinp[gm+1] = f2bf( LN(acc + bias) + residual[gm] )
__global__ __launch_bounds__(512) void gemm_ln0(
    const unsigned short* __restrict__ A, int lda,
    const unsigned short* __restrict__ B,         // ldb = 256, K = 256
    const float* __restrict__ bias,
    const float* __restrict__ residual,
    unsigned short* __restrict__ out_bf)
{
    __shared__ unsigned short As[64][72];
    __shared__ unsigned short Bs[256][72];
    __shared__ float redS[64][4];
    __shared__ float redQ[64][4];

    const int tid = threadIdx.x;
    const int lane = tid & 63;
    const int wid = tid >> 6;
    const int wm = wid >> 2, wn = wid & 3;
    const int m0 = blockIdx.x * 64;

    const int arow = tid >> 3, acol = (tid & 7) * 8;
    const int brow = tid >> 1, bcol = (tid & 1) * 32;
    const unsigned short* Ap = A + (size_t)(m0 + arow) * lda + acol;
    const unsigned short* Bp = B + (size_t)brow * 256 + bcol;

    u32x4 ra, rb0, rb1, rb2, rb3;
    auto loadregs = [&](int k0) {
        ra  = *(const u32x4*)(Ap + k0);
        rb0 = *(const u32x4*)(Bp + k0);
        rb1 = *(const u32x4*)(Bp + k0 + 8);
        rb2 = *(const u32x4*)(Bp + k0 + 16);
        rb3 = *(const u32x4*)(Bp + k0 + 24);
    };
    auto stlds = [&]() {
        *(u32x4*)&As[arow][acol]       = ra;
        *(u32x4*)&Bs[brow][bcol]       = rb0;
        *(u32x4*)&Bs[brow][bcol + 8]   = rb1;
        *(u32x4*)&Bs[brow][bcol + 16]  = rb2;
        *(u32x4*)&Bs[brow][bcol + 24]  = rb3;
    };

    f32x4 acc[2][4];
    #pragma unroll
    for (int i = 0; i < 2; ++i)
        #pragma unroll
        for (int j = 0; j < 4; ++j) acc[i][j] = (f32x4){0.f, 0.f, 0.f, 0.f};

    loadregs(0);
    stlds();
    __syncthreads();

    const int rowf = lane & 15, kb = lane >> 4;
    #pragma unroll
    for (int kt = 0; kt < 4; ++kt) {
        if (kt < 3) loadregs((kt + 1) << 6);
        #pragma unroll
        for (int ks = 0; ks < 2; ++ks) {
            bf16x8 af[2], bfr[4];
            #pragma unroll
            for (int i = 0; i < 2; ++i)
                af[i] = *(const bf16x8*)&As[wm * 32 + i * 16 + rowf][ks * 32 + kb * 8];
            #pragma unroll
            for (int j = 0; j < 4; ++j)
                bfr[j] = *(const bf16x8*)&Bs[wn * 64 + j * 16 + rowf][ks * 32 + kb * 8];
            #pragma unroll
            for (int i = 0; i < 2; ++i)
                #pragma unroll
                for (int j = 0; j < 4; ++j)
                    acc[i][j] = __builtin_amdgcn_mfma_f32_16x16x32_bf16(af[i], bfr[j], acc[i][j], 0, 0, 0);
        }
        __syncthreads();
        if (kt < 3) { stlds(); __syncthreads(); }
    }

    const int rq = lane >> 4;
    float val[2][4][4];
    #pragma unroll
    for (int i = 0; i < 2; ++i)
        #pragma unroll
        for (int j = 0; j < 4; ++j) {
            int gn = wn * 64 + j * 16 + rowf;
            float bv = bias[gn];
            #pragma unroll
            for (int r = 0; r < 4; ++r) val[i][j][r] = acc[i][j][r] + bv;
        }

    #pragma unroll
    for (int i = 0; i < 2; ++i)
        #pragma unroll
        for (int r = 0; r < 4; ++r) {
            float s = val[i][0][r] + val[i][1][r] + val[i][2][r] + val[i][3][r];
            float q = val[i][0][r] * val[i][0][r] + val[i][1][r] * val[i][1][r]
                    + val[i][2][r] * val[i][2][r] + val[i][3][r] * val[i][3][r];
            #pragma unroll
            for (int m = 1; m < 16; m <<= 1) {
                s += __shfl_xor(s, m, 64);
                q += __shfl_xor(q, m, 64);
            }
            if (rowf == 0) {
                int row = wm * 32 + i * 16 + rq * 4 + r;
                redS[row][wn] = s;
                redQ[row][wn] = q;
            }
        }
    __syncthreads();

    #pragma unroll
    for (int i = 0; i < 2; ++i) {
        #pragma unroll
        for (int r = 0; r < 4; ++r) {
            int row = wm * 32 + i * 16 + rq * 4 + r;
            int gm = m0 + row;
            float s = redS[row][0] + redS[row][1] + redS[row][2] + redS[row][3];
            float q = redQ[row][0] + redQ[row][1] + redQ[row][2] + redQ[row][3];
            float mu = s * (1.f / 256.f);
            float var = q * (1.f / 256.f) - mu * mu;
            float rs = rsqrtf(var + EPS);
            #pragma unroll
            for (int j = 0; j < 4; ++j) {
                int gn = wn * 64 + j * 16 + rowf;
                float nv = (val[i][j][r] - mu) * rs + residual[(size_t)gm * 256 + gn];
                out_bf[(size_t)(gm + 1) * 256 + gn] = f2bf(nv);
            }
        }
    }
}

// ================= banded attention =================
__global__ __launch_bounds__(256) void attn16(
    const unsigned short* __restrict__ q,
    const unsigned short* __restrict__ k,
    const unsigned short* __restrict__ v,
    unsigned short* __restrict__ ctx, int L)
{
    __shared__ unsigned short ksm[30][264];
    __shared__ unsigned short vsm[30][264];
    const int j0 = blockIdx.x * 16;
    const int iblk0 = (j0 >= 68) ? (j0 - 64) / 5 : 0;
    int ihim = (j0 + 79) / 5; if (ihim > L - 1) ihim = L - 1;
    const int NR = ihim - iblk0 + 1;

    for (int e = threadIdx.x; e < 30 * 32; e += 256) {
        int rr = e >> 5, cc = (e & 31) * 8;
        u32x4 kz = {0, 0, 0, 0}, vz = {0, 0, 0, 0};
        if (rr < NR) {
            kz = *(const u32x4*)&k[(size_t)(iblk0 + rr) * 256 + cc];
            vz = *(const u32x4*)&v[(size_t)(iblk0 + rr) * 256 + cc];
        }
        *(u32x4*)&ksm[rr][cc] = kz;
        *(u32x4*)&vsm[rr][cc] = vz;
    }
    __syncthreads();

    const int tid = threadIdx.x;
    const int h = tid >> 6, lane = tid & 63;
    const int qq = lane & 15, p = lane >> 4;
    const int j = j0 + qq;
    const int colb = h * 64 + p * 16;

    float qr[16];
    {
        u32x4 q0 = *(const u32x4*)&q[(size_t)j * 256 + colb];
        u32x4 q1 = *(const u32x4*)&q[(size_t)j * 256 + colb + 8];
        #pragma unroll
        for (int w = 0; w < 4; ++w) {
            qr[2 * w]     = bflo(q0[w]) * 0.125f;
            qr[2 * w + 1] = bfhi(q0[w]) * 0.125f;
            qr[8 + 2 * w]     = bflo(q1[w]) * 0.125f;
            qr[8 + 2 * w + 1] = bfhi(q1[w]) * 0.125f;
        }
    }
    const int ilo = (j >= 68) ? (j - 64) / 5 : 0;
    int ihi = (j + 64) / 5; if (ihi > L - 1) ihi = L - 1;

    float sc[30];
    #pragma unroll
    for (int t = 0; t < 30; ++t) {
        int i = iblk0 + t;
        u32x4 k0 = *(const u32x4*)&ksm[t][colb];
        u32x4 k1 = *(const u32x4*)&ksm[t][colb + 8];
        float s = 0.f;
        #pragma unroll
        for (int w = 0; w < 4; ++w) {
            s += qr[2 * w]     * bflo(k0[w]);
            s += qr[2 * w + 1] * bfhi(k0[w]);
            s += qr[8 + 2 * w]     * bflo(k1[w]);
            s += qr[8 + 2 * w + 1] * bfhi(k1[w]);
        }
        s += __shfl_xor(s, 16, 64);
        s += __shfl_xor(s, 32, 64);
        sc[t] = (i >= ilo && i <= ihi) ? s : -1e30f;
    }
    float mx = -1e30f;
    #pragma unroll
    for (int t = 0; t < 30; ++t) mx = fmaxf(mx, sc[t]);
    float den = 0.f, o[16];
    #pragma unroll
    for (int d = 0; d < 16; ++d) o[d] = 0.f;
    #pragma unroll
    for (int t = 0; t < 30; ++t) {
        float pt = __expf(sc[t] - mx);
        den += pt;
        u32x4 v0 = *(const u32x4*)&vsm[t][colb];
        u32x4 v1 = *(const u32x4*)&vsm[t][colb + 8];
        #pragma unroll
        for (int w = 0; w < 4; ++w) {
            o[2 * w]     += pt * bflo(v0[w]);
            o[2 * w + 1] += pt * bfhi(v0[w]);
            o[8 + 2 * w]     += pt * bflo(v1[w]);
            o[8 + 2 * w + 1] += pt * bfhi(v1[w]);
        }
    }
    float inv = 1.f / den;
    #pragma unroll
    for (int d = 0; d < 16; ++d)
        ctx[(size_t)j * 256 + colb + d] = f2bf(o[d] * inv);
}

// ================= fused skip-GEMM + 4x conv(tanh) + final LN ==================
// block = 40 valid rows (window 48 computed, 50-row guarded act buffers)
// 512 threads = 8 waves, each wave 48 rows x 32 cols (3 m-tiles x 2 n-tiles)
#define CVALID 40
#define CWIN 48
__global__ __launch_bounds__(512) void conv_skip_ln(
    const unsigned short* __restrict__ cinp,   // padded (T+2)x256 bf16
    const unsigned short* __restrict__ Wcb,    // 4 x 256 x 768 bf16
    const float* __restrict__ conv_b,          // 4 x 256
    const unsigned short* __restrict__ Wsb,    // 256 x 256 bf16
    const float* __restrict__ b_skip,
    float* __restrict__ out, int T)
{
    extern __shared__ char smem[];
    typedef unsigned short u16;
    u16 (*actA)[264] = (u16(*)[264])smem;                        // 50 rows
    u16 (*actB)[264] = (u16(*)[264])(smem + 26400);              // 50 rows
    u16 (*Bsm)[256][72] = (u16(*)[256][72])(smem + 52800);       // [2][256][72]
    float (*redS)[8] = (float(*)[8])(smem + 126528);
    float (*redQ)[8] = (float(*)[8])(smem + 128064);

    const int tid = threadIdx.x;
    const int lane = tid & 63;
    const int wid = tid >> 6;            // n-wave 0..7
    const int rowf = lane & 15;
    const int kq = lane >> 4;            // K-block for frags / row-quarter for C
    const int t0 = blockIdx.x * CVALID;

    // ---- load input window: actA row b (0..49) = cnn_in[t0-5+b] (0 outside [0,T))
    for (int e = tid; e < 50 * 32; e += 512) {
        int b = e >> 5, c = (e & 31) * 8;
        int g = t0 - 5 + b;
        u32x4 z = {0, 0, 0, 0};
        if (g >= -1 && g <= T)
            z = *(const u32x4*)&cinp[(size_t)(g + 1) * 256 + c];
        *(u32x4*)&actA[b][c] = z;
    }
    if (tid < 256) actB[0][tid] = 0; else actB[49][tid - 256] = 0;
    __syncthreads();

    const int srow = tid >> 1, shalf = tid & 1;      // B staging: 256 rows x 2 halves
    u32x4 rg0, rg1, rg2, rg3;
    auto stage_load = [&](const u16* W, int ldbw, int kt) {
        const u16* p = W + (size_t)srow * ldbw + kt * 64 + shalf * 32;
        rg0 = *(const u32x4*)p;
        rg1 = *(const u32x4*)(p + 8);
        rg2 = *(const u32x4*)(p + 16);
        rg3 = *(const u32x4*)(p + 24);
    };
    auto stage_write = [&](int buf) {
        *(u32x4*)&Bsm[buf][srow][shalf * 32]      = rg0;
        *(u32x4*)&Bsm[buf][srow][shalf * 32 + 8]  = rg1;
        *(u32x4*)&Bsm[buf][srow][shalf * 32 + 16] = rg2;
        *(u32x4*)&Bsm[buf][srow][shalf * 32 + 24] = rg3;
    };

    // run one GEMM over the window: acc += act_in @ W^T (slices)
    // isconv: K=768, dt=kt>>2, cbase=(kt&3)*64 ; skip: K=256, dt=1, cbase=kt*64
    auto run_gemm = [&](const u16* W, int ldbw, int nkt, bool isconv,
                        u16 (*actin)[264], f32x4 (*acc)[2]) {
        stage_load(W, ldbw, 0);
        stage_write(0);
        __syncthreads();
        for (int kt = 0; kt < nkt; ++kt) {
            bool has_next = (kt + 1 < nkt);
            if (has_next) stage_load(W, ldbw, kt + 1);
            const int dt = isconv ? (kt >> 2) : 1;
            const int cbase = isconv ? ((kt & 3) * 64) : (kt * 64);
            #pragma unroll
            for (int ks = 0; ks < 2; ++ks) {
                bf16x8 af[3], bfr[2];
                #pragma unroll
                for (int i = 0; i < 3; ++i)
                    af[i] = *(const bf16x8*)&actin[i * 16 + rowf + dt][cbase + ks * 32 + kq * 8];
                #pragma unroll
                for (int j = 0; j < 2; ++j)
                    bfr[j] = *(const bf16x8*)&Bsm[kt & 1][wid * 32 + j * 16 + rowf][ks * 32 + kq * 8];
                #pragma unroll
                for (int i = 0; i < 3; ++i)
                    #pragma unroll
                    for (int j = 0; j < 2; ++j)
                        acc[i][j] = __builtin_amdgcn_mfma_f32_16x16x32_bf16(af[i], bfr[j], acc[i][j], 0, 0, 0);
            }
            if (has_next) stage_write((kt + 1) & 1);
            __syncthreads();
        }
    };

    // ---- skip GEMM first (actA still holds cnn_in)
    f32x4 skipacc[3][2];
    #pragma unroll
    for (int i = 0; i < 3; ++i)
        #pragma unroll
        for (int j = 0; j < 2; ++j) skipacc[i][j] = (f32x4){0.f, 0.f, 0.f, 0.f};
    run_gemm(Wsb, 256, 4, false, actA, skipacc);

    // ---- conv layers 1..4
    f32x4 cacc[3][2];
    const int gn0 = wid * 32 + rowf;          // col for j=0 (j=1 adds 16)
    #pragma unroll 1
    for (int l = 0; l < 4; ++l) {
        #pragma unroll
        for (int i = 0; i < 3; ++i)
            #pragma unroll
            for (int j = 0; j < 2; ++j) cacc[i][j] = (f32x4){0.f, 0.f, 0.f, 0.f};
        u16 (*ain)[264]  = (l & 1) ? actB : actA;
        u16 (*aout)[264] = (l & 1) ? actA : actB;
        run_gemm(Wcb + (size_t)l * 196608, 768, 12, true, ain, cacc);

        float b0 = conv_b[l * 256 + gn0];
        float b1 = conv_b[l * 256 + gn0 + 16];
        if (l < 3) {
            #pragma unroll
            for (int i = 0; i < 3; ++i)
                #pragma unroll
                for (int r = 0; r < 4; ++r) {
                    int w = i * 16 + kq * 4 + r;
                    int g = t0 - 4 + w;
                    bool ok = (g >= 0 && g < T);
                    float v0 = cacc[i][0][r] + b0;
                    float v1 = cacc[i][1][r] + b1;
                    v0 = 1.f - 2.f / (__expf(2.f * v0) + 1.f);
                    v1 = 1.f - 2.f / (__expf(2.f * v1) + 1.f);
                    aout[w + 1][gn0]      = ok ? f2bf(v0) : (u16)0;
                    aout[w + 1][gn0 + 16] = ok ? f2bf(v1) : (u16)0;
                }
            if (tid < 256) aout[0][tid] = 0; else aout[49][tid - 256] = 0;
            // next run_gemm's first barrier orders these writes before reads
        } else {
            // final: val = tanh(conv4) + skip + b_skip, then LN
            float sb0 = b_skip[gn0], sb1 = b_skip[gn0 + 16];
            #pragma unroll
            for (int i = 0; i < 3; ++i)
                #pragma unroll
                for (int r = 0; r < 4; ++r) {
                    int w = i * 16 + kq * 4 + r;
                    int g = t0 - 4 + w;
                    bool ok = (g >= 0 && g < T);
                    float v0 = cacc[i][0][r] + b0;
                    float v1 = cacc[i][1][r] + b1;
                    v0 = ok ? (1.f - 2.f / (__expf(2.f * v0) + 1.f)) : 0.f;
                    v1 = ok ? (1.f - 2.f / (__expf(2.f * v1) + 1.f)) : 0.f;
                    skipacc[i][0][r] += sb0 + v0;
                    skipacc[i][1][r] += sb1 + v1;
                }
        }
    }

    // ---- LayerNorm over valid rows
    #pragma unroll
    for (int i = 0; i < 3; ++i)
        #pragma unroll
        for (int r = 0; r < 4; ++r) {
            float a = skipacc[i][0][r], b = skipacc[i][1][r];
            float s = a + b;
            float q = a * a + b * b;
            #pragma unroll
            for (int m = 1; m < 16; m <<= 1) {
                s += __shfl_xor(s, m, 64);
                q += __shfl_xor(q, m, 64);
            }
            if (rowf == 0) {
                int row = i * 16 + kq * 4 + r;
                redS[row][wid] = s;
                redQ[row][wid] = q;
            }
        }
    __syncthreads();

    #pragma unroll
    for (int i = 0; i < 3; ++i)
        #pragma unroll
        for (int r = 0; r < 4; ++r) {
            int row = i * 16 + kq * 4 + r;
            if (row < 4 || row >= 44) continue;
            int g = t0 - 4 + row;
            if (g >= T) continue;
            float s = 0.f, q = 0.f;
            #pragma unroll
            for (int x = 0; x < 8; ++x) { s += redS[row][x]; q += redQ[row][x]; }
            float mu = s * (1.f / 256.f);
            float var = q * (1.f / 256.f) - mu * mu;
            float rs = rsqrtf(var + EPS);
            out[(size_t)g * 256 + gn0]      = (skipacc[i][0][r] - mu) * rs;
            out[(size_t)g * 256 + gn0 + 16] = (skipacc[i][1][r] - mu) * rs;
        }
}

extern "C" void kernel_launch(void* const* d_in, const int* in_sizes, int n_in,
                              void* d_out, int out_size, void* d_ws, size_t ws_size,
                              hipStream_t stream) {
    const float* input    = (const float*)d_in[0];
    const float* residual = (const float*)d_in[1];
    const float* W_proj   = (const float*)d_in[2];
    const float* b_proj   = (const float*)d_in[3];
    const float* Wq       = (const float*)d_in[4];
    const float* bq       = (const float*)d_in[5];
    const float* Wk       = (const float*)d_in[6];
    const float* bk       = (const float*)d_in[7];
    const float* Wv       = (const float*)d_in[8];
    const float* bv       = (const float*)d_in[9];
    const float* Wo       = (const float*)d_in[10];
    const float* bo       = (const float*)d_in[11];
    const float* conv_w   = (const float*)d_in[12];
    const float* conv_b   = (const float*)d_in[13];
    const float* W_skip   = (const float*)d_in[14];
    const float* b_skip   = (const float*)d_in[15];
    float* out = (float*)d_out;

    const int L = in_sizes[0] / PROJ;   // 2048
    const int T = 5 * L;                // 10240

    unsigned short* w16 = (unsigned short*)d_ws;
    size_t off = 0;
    auto alloc = [&](size_t n) { unsigned short* p = w16 + off; off += n; return p; };
    unsigned short* Wpb  = alloc((size_t)1280 * 192);
    unsigned short* Wqb  = alloc(256 * 256);
    unsigned short* Wkb  = alloc(256 * 192);
    unsigned short* Wvb  = alloc(256 * 192);
    unsigned short* Wob  = alloc(256 * 256);
    unsigned short* Wsb  = alloc(256 * 256);
    unsigned short* Wcb  = alloc((size_t)4 * 256 * 768);
    unsigned short* srcb = alloc((size_t)L * KPAD);
    unsigned short* tgtb = alloc((size_t)T * 256);       // tgt, then ctx
    unsigned short* qb   = alloc((size_t)T * 256);       // q
    unsigned short* kb   = alloc((size_t)L * 256);
    unsigned short* vb   = alloc((size_t)L * 256);
    unsigned short* cinp = alloc((size_t)(T + 2) * 256); // padded cnn_in

    // 1) prep (1720832 elements = 6722 blocks)
    prep_all<<<dim3(6722), 256, 0, stream>>>(
        W_proj, Wq, Wk, Wv, Wo, W_skip, conv_w, input,
        Wpb, Wqb, Wkb, Wvb, Wob, Wsb, Wcb, srcb, cinp, L, T);

    // 2) tgt = src @ W_proj^T
    gemm_proj<<<dim3(1280 / 128, L / 64), 256, 0, stream>>>(
        srcb, KPAD, Wpb, 192, b_proj, tgtb, 1280, 192);

    // 3) q/k/v fused
    qkv_fused<<<dim3(448), 256, 0, stream>>>(
        tgtb, srcb, Wqb, Wkb, Wvb, bq, bk, bv, qb, kb, vb);

    // 4) attention -> ctx (reuse tgtb)
    attn16<<<dim3(T / 16), 256, 0, stream>>>(qb, kb, vb, tgtb, L);

    // 5) cnn_in = LN(ctx @ Wo^T + bo) + residual
    gemm_ln0<<<dim3(T / 64), 512, 0, stream>>>(tgtb, 256, Wob, bo, residual, cinp);

    // 6) fused skip-GEMM + conv stack + LN -> out
    hipFuncSetAttribute((const void*)conv_skip_ln,
                        hipFuncAttributeMaxDynamicSharedMemorySize, 131072);
    conv_skip_ln<<<dim3(T / CVALID), 512, 129600, stream>>>(
        cinp, Wcb, conv_b, Wsb, b_skip, out, T);
}

// Round 5
// 93.554 us; speedup vs baseline: 1.3616x; 1.3616x over previous
//
#include <hip/hip_runtime.h>
#include <hip/hip_bf16.h>

#define PROJ 128
#define KPAD 192
#define EPS 1e-5f

typedef __attribute__((ext_vector_type(4))) float f32x4;
typedef __attribute__((ext_vector_type(8))) short bf16x8;
typedef __attribute__((ext_vector_type(4))) unsigned int u32x4;

__device__ inline float bflo(unsigned u){ union{unsigned x;float f;}c; c.x = u<<16; return c.f; }
__device__ inline float bfhi(unsigned u){ union{unsigned x;float f;}c; c.x = u & 0xffff0000u; return c.f; }
__device__ inline float bf2f(unsigned short u){ union{unsigned x;float f;}c; c.x = ((unsigned)u)<<16; return c.f; }
__device__ inline unsigned short f2bf(float f){
    union{float f; unsigned u;} c; c.f = f;
    unsigned r = c.u + 0x7fff + ((c.u >> 16) & 1);
    return (unsigned short)(r >> 16);
}

// ================= prep: weight conversion (+ fragment packing) + src + pads =====
// Wsb/Wcb are packed in per-(kt, wave) MFMA-fragment order:
//   idx = (((ktl)*8 + wid)*4 + (j*2+ks))*512 + lane*8 + e
//   -> row o = wid*32 + j*16 + (lane&15), col c = kt*64 + ks*32 + (lane>>4)*8 + e
__global__ __launch_bounds__(256) void prep_all(
    const float* __restrict__ W_proj, const float* __restrict__ Wq,
    const float* __restrict__ Wk, const float* __restrict__ Wv,
    const float* __restrict__ Wo, const float* __restrict__ Ws,
    const float* __restrict__ convw, const float* __restrict__ input,
    unsigned short* __restrict__ Wpb, unsigned short* __restrict__ Wqb,
    unsigned short* __restrict__ Wkb, unsigned short* __restrict__ Wvb,
    unsigned short* __restrict__ Wob, unsigned short* __restrict__ Wsb,
    unsigned short* __restrict__ Wcb, unsigned short* __restrict__ srcb,
    unsigned short* __restrict__ cinp, int L, int T)
{
    int idx = blockIdx.x * 256 + threadIdx.x;
    if (idx < 245760) {
        int r = idx / 192, c = idx % 192;
        Wpb[idx] = (c < 136) ? f2bf(W_proj[(size_t)r * 136 + c]) : (unsigned short)0;
        return;
    }
    idx -= 245760;
    if (idx < 65536) { Wqb[idx] = f2bf(Wq[idx]); return; }
    idx -= 65536;
    if (idx < 49152) {
        int r = idx / 192, c = idx % 192;
        Wkb[idx] = (c < 136) ? f2bf(Wk[(size_t)r * 136 + c]) : (unsigned short)0;
        return;
    }
    idx -= 49152;
    if (idx < 49152) {
        int r = idx / 192, c = idx % 192;
        Wvb[idx] = (c < 136) ? f2bf(Wv[(size_t)r * 136 + c]) : (unsigned short)0;
        return;
    }
    idx -= 49152;
    if (idx < 65536) { Wob[idx] = f2bf(Wo[idx]); return; }
    idx -= 65536;
    if (idx < 65536) {
        // W_skip fragment-packed: kt in [0,4)
        int e = idx & 7;
        int lane = (idx >> 3) & 63;
        int fr = (idx >> 9) & 3;
        int wid = (idx >> 11) & 7;
        int kt = idx >> 14;
        int j = fr >> 1, ks = fr & 1;
        int kq = lane >> 4, rowf = lane & 15;
        int o = wid * 32 + j * 16 + rowf;
        int c = kt * 64 + ks * 32 + kq * 8 + e;
        Wsb[idx] = f2bf(Ws[(size_t)o * 256 + c]);
        return;
    }
    idx -= 65536;
    if (idx < 786432) {
        // conv weights fragment-packed: ktl = l*12 + kt
        int e = idx & 7;
        int lane = (idx >> 3) & 63;
        int fr = (idx >> 9) & 3;
        int wid = (idx >> 11) & 7;
        int ktl = idx >> 14;                 // [0,48)
        int l = ktl / 12, kt = ktl % 12;
        int j = fr >> 1, ks = fr & 1;
        int kq = lane >> 4, rowf = lane & 15;
        int o = wid * 32 + j * 16 + rowf;
        int c = kt * 64 + ks * 32 + kq * 8 + e;   // [0,768)
        int ktap = c >> 8, ci = c & 255;
        Wcb[idx] = f2bf(convw[(((size_t)l * 256 + o) * 256 + ci) * 3 + ktap]);
        return;
    }
    idx -= 786432;
    if (idx < L * KPAD) {
        int n = idx / KPAD, c = idx % KPAD;
        float v = 0.f;
        if (c < PROJ) v = input[(size_t)n * PROJ + c];
        else if (c < PROJ + 8) {
            int i = c - PROJ;
            int mask = (2 << i) - 1;
            v = (float)(n & mask) / (float)(1 << i);
        }
        srcb[idx] = f2bf(v);
        return;
    }
    idx -= L * KPAD;
    if (idx < 512) {
        int row = idx >> 8, c = idx & 255;
        size_t o = (row == 0) ? (size_t)c : (size_t)(T + 1) * 256 + c;
        cinp[o] = 0;
    }
}

// ================= shared 64x128 GEMM core =================
__device__ __forceinline__ void gemm_core_64x128(
    unsigned short (&As)[64][72], unsigned short (&Bs)[128][72],
    const unsigned short* __restrict__ A, int lda,
    const unsigned short* __restrict__ B, int ldb,
    const float* __restrict__ bias,
    unsigned short* __restrict__ C, int ldc,
    int K, int m0, int n0)
{
    const int tid = threadIdx.x;
    const int lane = tid & 63;
    const int wid = tid >> 6;
    const int wm = wid >> 1, wn = wid & 1;

    const int ar = tid >> 2, asg = tid & 3;
    const int br = tid >> 1, bsg = tid & 1;

    const unsigned short* Ap = A + (size_t)(m0 + ar) * lda + asg * 16;
    const unsigned short* Bp = B + (size_t)(n0 + br) * ldb + bsg * 32;

    u32x4 ra0, ra1, rb0, rb1, rb2, rb3;
    auto loadregs = [&](int k0) {
        ra0 = *(const u32x4*)(Ap + k0);
        ra1 = *(const u32x4*)(Ap + k0 + 8);
        rb0 = *(const u32x4*)(Bp + k0);
        rb1 = *(const u32x4*)(Bp + k0 + 8);
        rb2 = *(const u32x4*)(Bp + k0 + 16);
        rb3 = *(const u32x4*)(Bp + k0 + 24);
    };
    auto stlds = [&]() {
        *(u32x4*)&As[ar][asg * 16]      = ra0;
        *(u32x4*)&As[ar][asg * 16 + 8]  = ra1;
        *(u32x4*)&Bs[br][bsg * 32]      = rb0;
        *(u32x4*)&Bs[br][bsg * 32 + 8]  = rb1;
        *(u32x4*)&Bs[br][bsg * 32 + 16] = rb2;
        *(u32x4*)&Bs[br][bsg * 32 + 24] = rb3;
    };

    f32x4 acc[2][4];
    #pragma unroll
    for (int i = 0; i < 2; ++i)
        #pragma unroll
        for (int j = 0; j < 4; ++j) acc[i][j] = (f32x4){0.f, 0.f, 0.f, 0.f};

    loadregs(0);
    stlds();
    __syncthreads();

    const int rowf = lane & 15, kb = lane >> 4;
    const int ktiles = K >> 6;
    for (int kt = 0; kt < ktiles; ++kt) {
        if (kt + 1 < ktiles) loadregs((kt + 1) << 6);
        #pragma unroll
        for (int ks = 0; ks < 2; ++ks) {
            bf16x8 af[2], bfr[4];
            #pragma unroll
            for (int i = 0; i < 2; ++i)
                af[i] = *(const bf16x8*)&As[wm * 32 + i * 16 + rowf][ks * 32 + kb * 8];
            #pragma unroll
            for (int j = 0; j < 4; ++j)
                bfr[j] = *(const bf16x8*)&Bs[wn * 64 + j * 16 + rowf][ks * 32 + kb * 8];
            #pragma unroll
            for (int i = 0; i < 2; ++i)
                #pragma unroll
                for (int j = 0; j < 4; ++j)
                    acc[i][j] = __builtin_amdgcn_mfma_f32_16x16x32_bf16(af[i], bfr[j], acc[i][j], 0, 0, 0);
        }
        __syncthreads();
        if (kt + 1 < ktiles) { stlds(); __syncthreads(); }
    }

    const int rq = lane >> 4;
    #pragma unroll
    for (int i = 0; i < 2; ++i) {
        int gm = m0 + wm * 32 + i * 16 + rq * 4;
        #pragma unroll
        for (int j = 0; j < 4; ++j) {
            int gn = n0 + wn * 64 + j * 16 + rowf;
            float bv = bias[gn];
            #pragma unroll
            for (int r = 0; r < 4; ++r)
                C[(size_t)(gm + r) * ldc + gn] = f2bf(acc[i][j][r] + bv);
        }
    }
}

__global__ __launch_bounds__(256) void gemm_proj(
    const unsigned short* __restrict__ A, int lda,
    const unsigned short* __restrict__ B, int ldb,
    const float* __restrict__ bias,
    unsigned short* __restrict__ C, int ldc, int K)
{
    __shared__ unsigned short As[64][72];
    __shared__ unsigned short Bs[128][72];
    gemm_core_64x128(As, Bs, A, lda, B, ldb, bias, C, ldc, K,
                     blockIdx.y * 64, blockIdx.x * 128);
}

// q/k/v in one launch: blocks [0,320)=q, [320,384)=k, [384,448)=v
__global__ __launch_bounds__(256) void qkv_fused(
    const unsigned short* __restrict__ tgt,
    const unsigned short* __restrict__ src,
    const unsigned short* __restrict__ Wqb,
    const unsigned short* __restrict__ Wkb,
    const unsigned short* __restrict__ Wvb,
    const float* __restrict__ bq, const float* __restrict__ bk,
    const float* __restrict__ bv,
    unsigned short* __restrict__ qb, unsigned short* __restrict__ kb,
    unsigned short* __restrict__ vb)
{
    __shared__ unsigned short As[64][72];
    __shared__ unsigned short Bs[128][72];
    int bi = blockIdx.x;
    const unsigned short *A, *B;
    const float* bias;
    unsigned short* C;
    int lda, ldb, K, m0, n0;
    if (bi < 320) {
        A = tgt; B = Wqb; bias = bq; C = qb; lda = 256; ldb = 256; K = 256;
        m0 = (bi >> 1) * 64; n0 = (bi & 1) * 128;
    } else if (bi < 384) {
        int t = bi - 320;
        A = src; B = Wkb; bias = bk; C = kb; lda = KPAD; ldb = 192; K = 192;
        m0 = (t >> 1) * 64; n0 = (t & 1) * 128;
    } else {
        int t = bi - 384;
        A = src; B = Wvb; bias = bv; C = vb; lda = KPAD; ldb = 192; K = 192;
        m0 = (t >> 1) * 64; n0 = (t & 1) * 128;
    }
    gemm_core_64x128(As, Bs, A, lda, B, ldb, bias, C, 256, K, m0, n0);
}

// ================= 64x256-tile GEMM with fused LayerNorm epilogue (Wo path) ======
__global__ __launch_bounds__(512) void gemm_ln0(
    const unsigned short* __restrict__ A, int lda,
    const unsigned short* __restrict__ B,
    const float* __restrict__ bias,
    const float* __restrict__ residual,
    unsigned short* __restrict__ out_bf)
{
    __shared__ unsigned short As[64][72];
    __shared__ unsigned short Bs[256][72];
    __shared__ float redS[64][4];
    __shared__ float redQ[64][4];

    const int tid = threadIdx.x;
    const int lane = tid & 63;
    const int wid = tid >> 6;
    const int wm = wid >> 2, wn = wid & 3;
    const int m0 = blockIdx.x * 64;

    const int arow = tid >> 3, acol = (tid & 7) * 8;
    const int brow = tid >> 1, bcol = (tid & 1) * 32;
    const unsigned short* Ap = A + (size_t)(m0 + arow) * lda + acol;
    const unsigned short* Bp = B + (size_t)brow * 256 + bcol;

    u32x4 ra, rb0, rb1, rb2, rb3;
    auto loadregs = [&](int k0) {
        ra  = *(const u32x4*)(Ap + k0);
        rb0 = *(const u32x4*)(Bp + k0);
        rb1 = *(const u32x4*)(Bp + k0 + 8);
        rb2 = *(const u32x4*)(Bp + k0 + 16);
        rb3 = *(const u32x4*)(Bp + k0 + 24);
    };
    auto stlds = [&]() {
        *(u32x4*)&As[arow][acol]       = ra;
        *(u32x4*)&Bs[brow][bcol]       = rb0;
        *(u32x4*)&Bs[brow][bcol + 8]   = rb1;
        *(u32x4*)&Bs[brow][bcol + 16]  = rb2;
        *(u32x4*)&Bs[brow][bcol + 24]  = rb3;
    };

    f32x4 acc[2][4];
    #pragma unroll
    for (int i = 0; i < 2; ++i)
        #pragma unroll
        for (int j = 0; j < 4; ++j) acc[i][j] = (f32x4){0.f, 0.f, 0.f, 0.f};

    loadregs(0);
    stlds();
    __syncthreads();

    const int rowf = lane & 15, kb = lane >> 4;
    #pragma unroll
    for (int kt = 0; kt < 4; ++kt) {
        if (kt < 3) loadregs((kt + 1) << 6);
        #pragma unroll
        for (int ks = 0; ks < 2; ++ks) {
            bf16x8 af[2], bfr[4];
            #pragma unroll
            for (int i = 0; i < 2; ++i)
                af[i] = *(const bf16x8*)&As[wm * 32 + i * 16 + rowf][ks * 32 + kb * 8];
            #pragma unroll
            for (int j = 0; j < 4; ++j)
                bfr[j] = *(const bf16x8*)&Bs[wn * 64 + j * 16 + rowf][ks * 32 + kb * 8];
            #pragma unroll
            for (int i = 0; i < 2; ++i)
                #pragma unroll
                for (int j = 0; j < 4; ++j)
                    acc[i][j] = __builtin_amdgcn_mfma_f32_16x16x32_bf16(af[i], bfr[j], acc[i][j], 0, 0, 0);
        }
        __syncthreads();
        if (kt < 3) { stlds(); __syncthreads(); }
    }

    const int rq = lane >> 4;
    float val[2][4][4];
    #pragma unroll
    for (int i = 0; i < 2; ++i)
        #pragma unroll
        for (int j = 0; j < 4; ++j) {
            int gn = wn * 64 + j * 16 + rowf;
            float bv = bias[gn];
            #pragma unroll
            for (int r = 0; r < 4; ++r) val[i][j][r] = acc[i][j][r] + bv;
        }

    #pragma unroll
    for (int i = 0; i < 2; ++i)
        #pragma unroll
        for (int r = 0; r < 4; ++r) {
            float s = val[i][0][r] + val[i][1][r] + val[i][2][r] + val[i][3][r];
            float q = val[i][0][r] * val[i][0][r] + val[i][1][r] * val[i][1][r]
                    + val[i][2][r] * val[i][2][r] + val[i][3][r] * val[i][3][r];
            #pragma unroll
            for (int m = 1; m < 16; m <<= 1) {
                s += __shfl_xor(s, m, 64);
                q += __shfl_xor(q, m, 64);
            }
            if (rowf == 0) {
                int row = wm * 32 + i * 16 + rq * 4 + r;
                redS[row][wn] = s;
                redQ[row][wn] = q;
            }
        }
    __syncthreads();

    #pragma unroll
    for (int i = 0; i < 2; ++i) {
        #pragma unroll
        for (int r = 0; r < 4; ++r) {
            int row = wm * 32 + i * 16 + rq * 4 + r;
            int gm = m0 + row;
            float s = redS[row][0] + redS[row][1] + redS[row][2] + redS[row][3];
            float q = redQ[row][0] + redQ[row][1] + redQ[row][2] + redQ[row][3];
            float mu = s * (1.f / 256.f);
            float var = q * (1.f / 256.f) - mu * mu;
            float rs = rsqrtf(var + EPS);
            #pragma unroll
            for (int j = 0; j < 4; ++j) {
                int gn = wn * 64 + j * 16 + rowf;
                float nv = (val[i][j][r] - mu) * rs + residual[(size_t)gm * 256 + gn];
                out_bf[(size_t)(gm + 1) * 256 + gn] = f2bf(nv);
            }
        }
    }
}

// ================= banded attention =================
__global__ __launch_bounds__(256) void attn16(
    const unsigned short* __restrict__ q,
    const unsigned short* __restrict__ k,
    const unsigned short* __restrict__ v,
    unsigned short* __restrict__ ctx, int L)
{
    __shared__ unsigned short ksm[30][264];
    __shared__ unsigned short vsm[30][264];
    const int j0 = blockIdx.x * 16;
    const int iblk0 = (j0 >= 68) ? (j0 - 64) / 5 : 0;
    int ihim = (j0 + 79) / 5; if (ihim > L - 1) ihim = L - 1;
    const int NR = ihim - iblk0 + 1;

    for (int e = threadIdx.x; e < 30 * 32; e += 256) {
        int rr = e >> 5, cc = (e & 31) * 8;
        u32x4 kz = {0, 0, 0, 0}, vz = {0, 0, 0, 0};
        if (rr < NR) {
            kz = *(const u32x4*)&k[(size_t)(iblk0 + rr) * 256 + cc];
            vz = *(const u32x4*)&v[(size_t)(iblk0 + rr) * 256 + cc];
        }
        *(u32x4*)&ksm[rr][cc] = kz;
        *(u32x4*)&vsm[rr][cc] = vz;
    }
    __syncthreads();

    const int tid = threadIdx.x;
    const int h = tid >> 6, lane = tid & 63;
    const int qq = lane & 15, p = lane >> 4;
    const int j = j0 + qq;
    const int colb = h * 64 + p * 16;

    float qr[16];
    {
        u32x4 q0 = *(const u32x4*)&q[(size_t)j * 256 + colb];
        u32x4 q1 = *(const u32x4*)&q[(size_t)j * 256 + colb + 8];
        #pragma unroll
        for (int w = 0; w < 4; ++w) {
            qr[2 * w]     = bflo(q0[w]) * 0.125f;
            qr[2 * w + 1] = bfhi(q0[w]) * 0.125f;
            qr[8 + 2 * w]     = bflo(q1[w]) * 0.125f;
            qr[8 + 2 * w + 1] = bfhi(q1[w]) * 0.125f;
        }
    }
    const int ilo = (j >= 68) ? (j - 64) / 5 : 0;
    int ihi = (j + 64) / 5; if (ihi > L - 1) ihi = L - 1;

    float sc[30];
    #pragma unroll
    for (int t = 0; t < 30; ++t) {
        int i = iblk0 + t;
        u32x4 k0 = *(const u32x4*)&ksm[t][colb];
        u32x4 k1 = *(const u32x4*)&ksm[t][colb + 8];
        float s = 0.f;
        #pragma unroll
        for (int w = 0; w < 4; ++w) {
            s += qr[2 * w]     * bflo(k0[w]);
            s += qr[2 * w + 1] * bfhi(k0[w]);
            s += qr[8 + 2 * w]     * bflo(k1[w]);
            s += qr[8 + 2 * w + 1] * bfhi(k1[w]);
        }
        s += __shfl_xor(s, 16, 64);
        s += __shfl_xor(s, 32, 64);
        sc[t] = (i >= ilo && i <= ihi) ? s : -1e30f;
    }
    float mx = -1e30f;
    #pragma unroll
    for (int t = 0; t < 30; ++t) mx = fmaxf(mx, sc[t]);
    float den = 0.f, o[16];
    #pragma unroll
    for (int d = 0; d < 16; ++d) o[d] = 0.f;
    #pragma unroll
    for (int t = 0; t < 30; ++t) {
        float pt = __expf(sc[t] - mx);
        den += pt;
        u32x4 v0 = *(const u32x4*)&vsm[t][colb];
        u32x4 v1 = *(const u32x4*)&vsm[t][colb + 8];
        #pragma unroll
        for (int w = 0; w < 4; ++w) {
            o[2 * w]     += pt * bflo(v0[w]);
            o[2 * w + 1] += pt * bfhi(v0[w]);
            o[8 + 2 * w]     += pt * bflo(v1[w]);
            o[8 + 2 * w + 1] += pt * bfhi(v1[w]);
        }
    }
    float inv = 1.f / den;
    #pragma unroll
    for (int d = 0; d < 16; ++d)
        ctx[(size_t)j * 256 + colb + d] = f2bf(o[d] * inv);
}

// ================= fused skip-GEMM + 4x conv(tanh) + final LN (v2) ==============
// Weights per-wave from global (fragment-packed, coalesced, 2-deep reg prefetch);
// LDS holds only activations -> NO per-K-step barriers, no Bsm.
#define CVALID 40
template<int NKT, bool ISCONV>
__device__ __forceinline__ void frag_gemm(
    const unsigned short* __restrict__ Wp,     // packed base for this pass/layer
    unsigned short (*actin)[264],
    f32x4 (&acc)[3][2], int wid, int lane)
{
    const int rowf = lane & 15, kq = lane >> 4;
    const unsigned short* base = Wp + wid * 2048 + lane * 8;
    bf16x8 b0, b1, b2, b3, c0, c1, c2, c3, d0, d1, d2, d3;
    b0 = *(const bf16x8*)(base);
    b1 = *(const bf16x8*)(base + 512);
    b2 = *(const bf16x8*)(base + 1024);
    b3 = *(const bf16x8*)(base + 1536);
    c0 = *(const bf16x8*)(base + 16384);
    c1 = *(const bf16x8*)(base + 16384 + 512);
    c2 = *(const bf16x8*)(base + 16384 + 1024);
    c3 = *(const bf16x8*)(base + 16384 + 1536);
    d0 = b0; d1 = b1; d2 = b2; d3 = b3;
    #pragma unroll
    for (int kt = 0; kt < NKT; ++kt) {
        if (kt + 2 < NKT) {
            const unsigned short* nb = base + (kt + 2) * 16384;
            d0 = *(const bf16x8*)(nb);
            d1 = *(const bf16x8*)(nb + 512);
            d2 = *(const bf16x8*)(nb + 1024);
            d3 = *(const bf16x8*)(nb + 1536);
        }
        const int dt = ISCONV ? (kt >> 2) : 1;
        const int cb = ISCONV ? ((kt & 3) * 64) : (kt * 64);
        #pragma unroll
        for (int ks = 0; ks < 2; ++ks) {
            bf16x8 a0 = *(const bf16x8*)&actin[rowf + dt][cb + ks * 32 + kq * 8];
            bf16x8 a1 = *(const bf16x8*)&actin[16 + rowf + dt][cb + ks * 32 + kq * 8];
            bf16x8 a2 = *(const bf16x8*)&actin[32 + rowf + dt][cb + ks * 32 + kq * 8];
            bf16x8 w0 = ks ? b1 : b0;
            bf16x8 w1 = ks ? b3 : b2;
            acc[0][0] = __builtin_amdgcn_mfma_f32_16x16x32_bf16(a0, w0, acc[0][0], 0, 0, 0);
            acc[0][1] = __builtin_amdgcn_mfma_f32_16x16x32_bf16(a0, w1, acc[0][1], 0, 0, 0);
            acc[1][0] = __builtin_amdgcn_mfma_f32_16x16x32_bf16(a1, w0, acc[1][0], 0, 0, 0);
            acc[1][1] = __builtin_amdgcn_mfma_f32_16x16x32_bf16(a1, w1, acc[1][1], 0, 0, 0);
            acc[2][0] = __builtin_amdgcn_mfma_f32_16x16x32_bf16(a2, w0, acc[2][0], 0, 0, 0);
            acc[2][1] = __builtin_amdgcn_mfma_f32_16x16x32_bf16(a2, w1, acc[2][1], 0, 0, 0);
        }
        b0 = c0; b1 = c1; b2 = c2; b3 = c3;
        c0 = d0; c1 = d1; c2 = d2; c3 = d3;
    }
}

__global__ __launch_bounds__(512, 2) void conv_skip_ln(
    const unsigned short* __restrict__ cinp,   // padded (T+2)x256 bf16
    const unsigned short* __restrict__ Wcb,    // packed 4*12*8*4*512
    const float* __restrict__ conv_b,
    const unsigned short* __restrict__ Wsb,    // packed 4*8*4*512
    const float* __restrict__ b_skip,
    float* __restrict__ out, int T)
{
    __shared__ unsigned short actA[50][264];
    __shared__ unsigned short actB[50][264];
    __shared__ float redS[48][8];
    __shared__ float redQ[48][8];

    const int tid = threadIdx.x;
    const int lane = tid & 63;
    const int wid = tid >> 6;
    const int rowf = lane & 15;
    const int kq = lane >> 4;
    const int t0 = blockIdx.x * CVALID;

    // ---- load input window: actA row b = cnn_in[t0-5+b] (zeros outside)
    for (int e = tid; e < 50 * 32; e += 512) {
        int b = e >> 5, c = (e & 31) * 8;
        int g = t0 - 5 + b;
        u32x4 z = {0, 0, 0, 0};
        if (g >= -1 && g <= T)
            z = *(const u32x4*)&cinp[(size_t)(g + 1) * 256 + c];
        *(u32x4*)&actA[b][c] = z;
    }
    if (tid < 256) actB[0][tid] = 0; else actB[49][tid - 256] = 0;
    __syncthreads();

    // ---- skip GEMM (actA holds cnn_in)
    f32x4 skipacc[3][2];
    #pragma unroll
    for (int i = 0; i < 3; ++i)
        #pragma unroll
        for (int j = 0; j < 2; ++j) skipacc[i][j] = (f32x4){0.f, 0.f, 0.f, 0.f};
    frag_gemm<4, false>(Wsb, actA, skipacc, wid, lane);

    // ---- conv layers
    const int gn0 = wid * 32 + rowf;
    f32x4 cacc[3][2];
    #pragma unroll 1
    for (int l = 0; l < 4; ++l) {
        #pragma unroll
        for (int i = 0; i < 3; ++i)
            #pragma unroll
            for (int j = 0; j < 2; ++j) cacc[i][j] = (f32x4){0.f, 0.f, 0.f, 0.f};
        unsigned short (*ain)[264]  = (l & 1) ? actB : actA;
        unsigned short (*aout)[264] = (l & 1) ? actA : actB;
        frag_gemm<12, true>(Wcb + (size_t)l * 196608, ain, cacc, wid, lane);

        float b0 = conv_b[l * 256 + gn0];
        float b1 = conv_b[l * 256 + gn0 + 16];
        if (l < 3) {
            #pragma unroll
            for (int i = 0; i < 3; ++i)
                #pragma unroll
                for (int r = 0; r < 4; ++r) {
                    int w = i * 16 + kq * 4 + r;
                    int g = t0 - 4 + w;
                    bool ok = (g >= 0 && g < T);
                    float v0 = cacc[i][0][r] + b0;
                    float v1 = cacc[i][1][r] + b1;
                    v0 = 1.f - 2.f / (__expf(2.f * v0) + 1.f);
                    v1 = 1.f - 2.f / (__expf(2.f * v1) + 1.f);
                    aout[w + 1][gn0]      = ok ? f2bf(v0) : (unsigned short)0;
                    aout[w + 1][gn0 + 16] = ok ? f2bf(v1) : (unsigned short)0;
                }
            if (tid < 256) aout[0][tid] = 0; else aout[49][tid - 256] = 0;
            __syncthreads();
        } else {
            float sb0 = b_skip[gn0], sb1 = b_skip[gn0 + 16];
            #pragma unroll
            for (int i = 0; i < 3; ++i)
                #pragma unroll
                for (int r = 0; r < 4; ++r) {
                    int w = i * 16 + kq * 4 + r;
                    int g = t0 - 4 + w;
                    bool ok = (g >= 0 && g < T);
                    float v0 = cacc[i][0][r] + b0;
                    float v1 = cacc[i][1][r] + b1;
                    v0 = ok ? (1.f - 2.f / (__expf(2.f * v0) + 1.f)) : 0.f;
                    v1 = ok ? (1.f - 2.f / (__expf(2.f * v1) + 1.f)) : 0.f;
                    skipacc[i][0][r] += sb0 + v0;
                    skipacc[i][1][r] += sb1 + v1;
                }
        }
    }

    // ---- LayerNorm over valid rows
    #pragma unroll
    for (int i = 0; i < 3; ++i)
        #pragma unroll
        for (int r = 0; r < 4; ++r) {
            float a = skipacc[i][0][r], b = skipacc[i][1][r];
            float s = a + b;
            float q = a * a + b * b;
            #pragma unroll
            for (int m = 1; m < 16; m <<= 1) {
                s += __shfl_xor(s, m, 64);
                q += __shfl_xor(q, m, 64);
            }
            if (rowf == 0) {
                int row = i * 16 + kq * 4 + r;
                redS[row][wid] = s;
                redQ[row][wid] = q;
            }
        }
    __syncthreads();

    #pragma unroll
    for (int i = 0; i < 3; ++i)
        #pragma unroll
        for (int r = 0; r < 4; ++r) {
            int row = i * 16 + kq * 4 + r;
            if (row < 4 || row >= 44) continue;
            int g = t0 - 4 + row;
            if (g >= T) continue;
            float s = 0.f, q = 0.f;
            #pragma unroll
            for (int x = 0; x < 8; ++x) { s += redS[row][x]; q += redQ[row][x]; }
            float mu = s * (1.f / 256.f);
            float var = q * (1.f / 256.f) - mu * mu;
            float rs = rsqrtf(var + EPS);
            out[(size_t)g * 256 + gn0]      = (skipacc[i][0][r] - mu) * rs;
            out[(size_t)g * 256 + gn0 + 16] = (skipacc[i][1][r] - mu) * rs;
        }
}

extern "C" void kernel_launch(void* const* d_in, const int* in_sizes, int n_in,
                              void* d_out, int out_size, void* d_ws, size_t ws_size,
                              hipStream_t stream) {
    const float* input    = (const float*)d_in[0];
    const float* residual = (const float*)d_in[1];
    const float* W_proj   = (const float*)d_in[2];
    const float* b_proj   = (const float*)d_in[3];
    const float* Wq       = (const float*)d_in[4];
    const float* bq       = (const float*)d_in[5];
    const float* Wk       = (const float*)d_in[6];
    const float* bk       = (const float*)d_in[7];
    const float* Wv       = (const float*)d_in[8];
    const float* bv       = (const float*)d_in[9];
    const float* Wo       = (const float*)d_in[10];
    const float* bo       = (const float*)d_in[11];
    const float* conv_w   = (const float*)d_in[12];
    const float* conv_b   = (const float*)d_in[13];
    const float* W_skip   = (const float*)d_in[14];
    const float* b_skip   = (const float*)d_in[15];
    float* out = (float*)d_out;

    const int L = in_sizes[0] / PROJ;   // 2048
    const int T = 5 * L;                // 10240

    unsigned short* w16 = (unsigned short*)d_ws;
    size_t off = 0;
    auto alloc = [&](size_t n) { unsigned short* p = w16 + off; off += n; return p; };
    unsigned short* Wpb  = alloc((size_t)1280 * 192);
    unsigned short* Wqb  = alloc(256 * 256);
    unsigned short* Wkb  = alloc(256 * 192);
    unsigned short* Wvb  = alloc(256 * 192);
    unsigned short* Wob  = alloc(256 * 256);
    unsigned short* Wsb  = alloc(256 * 256);          // packed
    unsigned short* Wcb  = alloc((size_t)4 * 256 * 768); // packed
    unsigned short* srcb = alloc((size_t)L * KPAD);
    unsigned short* tgtb = alloc((size_t)T * 256);
    unsigned short* qb   = alloc((size_t)T * 256);
    unsigned short* kb   = alloc((size_t)L * 256);
    unsigned short* vb   = alloc((size_t)L * 256);
    unsigned short* cinp = alloc((size_t)(T + 2) * 256);

    // 1) prep (1720832 elements = 6722 blocks)
    prep_all<<<dim3(6722), 256, 0, stream>>>(
        W_proj, Wq, Wk, Wv, Wo, W_skip, conv_w, input,
        Wpb, Wqb, Wkb, Wvb, Wob, Wsb, Wcb, srcb, cinp, L, T);

    // 2) tgt = src @ W_proj^T
    gemm_proj<<<dim3(1280 / 128, L / 64), 256, 0, stream>>>(
        srcb, KPAD, Wpb, 192, b_proj, tgtb, 1280, 192);

    // 3) q/k/v fused
    qkv_fused<<<dim3(448), 256, 0, stream>>>(
        tgtb, srcb, Wqb, Wkb, Wvb, bq, bk, bv, qb, kb, vb);

    // 4) attention -> ctx (reuse tgtb)
    attn16<<<dim3(T / 16), 256, 0, stream>>>(qb, kb, vb, tgtb, L);

    // 5) cnn_in = LN(ctx @ Wo^T + bo) + residual
    gemm_ln0<<<dim3(T / 64), 512, 0, stream>>>(tgtb, 256, Wob, bo, residual, cinp);

    // 6) fused skip-GEMM + conv stack + LN -> out
    conv_skip_ln<<<dim3(T / CVALID), 512, 0, stream>>>(
        cinp, Wcb, conv_b, Wsb, b_skip, out, T);
}